// Round 1
// baseline (354.564 us; speedup 1.0000x reference)
//
#include <hip/hip_runtime.h>

typedef _Float16 half_t;
typedef __attribute__((ext_vector_type(8))) _Float16 half8;
typedef __attribute__((ext_vector_type(4))) _Float16 half4;
typedef __attribute__((ext_vector_type(4))) float float4_t;

#define BN_EPS 1e-5f

constexpr int Nn = 64, Cc = 64, Tt = 300, Vv = 25, Ss = 3;
constexpr int TB   = 8;              // timesteps per block
constexpr int TWN  = TB * Vv;        // 200 = stage-2 N dimension
constexpr int NT   = 13;             // 13 n-tiles of 16 cover 208 >= 200
constexpr int XL_T = 32;             // v-stride (padded 25->32, pads are ZERO = free K-pad)
constexpr int XL_C = TB * XL_T + 8;  // 264 halfs per c row (+8: bank-stride 4 -> 2-way, free)
constexpr int XA_S = 72;             // c-stride of xa rows (144 B: 16B-aligned, 2-way banks)
constexpr int XA_R = NT * 16;        // 208 rows
constexpr int AE_S = 40;             // v-stride of AeT rows (80 B, 16B-aligned)

__global__ __launch_bounds__(256, 2)
void gcn_fused(const float* __restrict__ x,   const float* __restrict__ A,
               const float* __restrict__ PA1, const float* __restrict__ PA2,
               const float* __restrict__ Wc,  const float* __restrict__ bc,
               const float* __restrict__ gamma, const float* __restrict__ beta,
               const float* __restrict__ rmean, const float* __restrict__ rvar,
               float* __restrict__ out)
{
    __shared__ __align__(16) half_t Xl[Cc * XL_C];       // 33792 B
    __shared__ __align__(16) half_t xaL[XA_R * XA_S];    // 29952 B
    __shared__ __align__(16) half_t AeT[Ss * 32 * AE_S]; // 7680 B
    __shared__ float bnsc[Cc], bnsh[Cc];                 // 512 B   (total ~72 KB -> 2 blocks/CU)

    const int tid  = threadIdx.x;
    const int lane = tid & 63;
    const int wave = tid >> 6;      // 0..3
    const int col  = lane & 15;     // MFMA n/m lane index
    const int quad = lane >> 4;     // 0..3

    const int tb = blockIdx.x;      // 0..37
    const int n  = blockIdx.y;      // 0..63
    const int t0 = tb * TB;

    // ---- BN scale/shift with Sum_s bc[s] folded in ----
    if (tid < Cc) {
        float sc   = gamma[tid] * rsqrtf(rvar[tid] + BN_EPS);
        float bsum = bc[tid] + bc[Cc + tid] + bc[2 * Cc + tid];
        bnsc[tid] = sc;
        bnsh[tid] = beta[tid] - rmean[tid] * sc + bsum * sc;
    }

    // ---- adaptive adjacency, transposed: AeT[s][w][v] = A*PA1 + PA2 ; v>=25 -> 0 (K-pad) ----
    for (int e = tid; e < Ss * 32 * 32; e += 256) {
        int s = e >> 10, r = e & 1023, w = r >> 5, v = r & 31;
        float val = 0.f;
        if (v < Vv && w < Vv) {
            int ai = (s * Vv + v) * Vv + w;
            val = A[ai] * PA1[ai] + PA2[ai];
        }
        AeT[(s * 32 + w) * AE_S + v] = (half_t)val;
    }

    // ---- zero the xa tail rows (tw 200..207 feed discarded MFMA columns) ----
    for (int e = tid; e < (XA_R - TWN) * XA_S; e += 256)
        xaL[TWN * XA_S + e] = (half_t)0.f;

    // ---- Wc A-fragments (this wave's o-tile), fp32 -> fp16, kept in registers ----
    half8 wf[Ss][2];
    {
        int o = wave * 16 + col;                 // A-frag: m = lane&15
        #pragma unroll
        for (int s = 0; s < Ss; ++s)
            #pragma unroll
            for (int ks = 0; ks < 2; ++ks) {
                const float* p = Wc + (s * Cc + o) * Cc + ks * 32 + quad * 8; // k = quad*8+j
                half8 h;
                #pragma unroll
                for (int j = 0; j < 8; ++j) h[j] = (half_t)p[j];
                wf[s][ks] = h;
            }
    }

    // ---- stage x slice into LDS: Xl[c][t][v], fp32->fp16, zero pads ----
    {
        const float* xb = x + (size_t)n * Cc * Tt * Vv + t0 * Vv;
        for (int slot = tid; slot < Cc * TB * 8; slot += 256) {
            int c = slot >> 6, rem = slot & 63, t = rem >> 3, k = rem & 7;
            int v0 = k * 4;
            half4 h;
            #pragma unroll
            for (int j = 0; j < 4; ++j) {
                int v = v0 + j;
                float f = (v < Vv && (t0 + t) < Tt) ? xb[c * Tt * Vv + t * Vv + v] : 0.f;
                h[j] = (half_t)f;
            }
            *(half4*)&Xl[c * XL_C + t * XL_T + v0] = h;   // 8B aligned
        }
    }
    __syncthreads();

    const float4_t zero4 = {0.f, 0.f, 0.f, 0.f};
    float4_t yacc[NT];
    #pragma unroll
    for (int i = 0; i < NT; ++i) yacc[i] = zero4;

    for (int s = 0; s < Ss; ++s) {
        // Ae B-frags for this s: B[k=v][n=w], n=col, k=quad*8+j
        half8 ab[2];
        #pragma unroll
        for (int wt = 0; wt < 2; ++wt)
            ab[wt] = *(const half8*)&AeT[(s * 32 + wt * 16 + col) * AE_S + quad * 8];

        // ---- stage 1: xa[c][(t,w)] = X · Ae[s], one MFMA per 16x16 tile (K=32 covers v=25) ----
        #pragma unroll
        for (int ti = 0; ti < 2; ++ti) {
            int t = wave * 2 + ti;
            #pragma unroll
            for (int ct = 0; ct < 4; ++ct) {
                // A-frag: m = c = ct*16+col, k = v = quad*8+j (v-pads are zero in Xl)
                half8 af = *(const half8*)&Xl[(ct * 16 + col) * XL_C + t * XL_T + quad * 8];
                #pragma unroll
                for (int wt = 0; wt < 2; ++wt) {
                    float4_t r = __builtin_amdgcn_mfma_f32_16x16x32_f16(af, ab[wt], zero4, 0, 0, 0);
                    int w = wt * 16 + col;           // C/D: col = lane&15
                    if (w < Vv) {
                        half4 h;
                        #pragma unroll
                        for (int i = 0; i < 4; ++i) h[i] = (half_t)r[i];  // rows = quad*4+i = consecutive c
                        *(half4*)&xaL[(t * Vv + w) * XA_S + ct * 16 + quad * 4] = h;
                    }
                }
            }
        }
        __syncthreads();

        // ---- stage 2: y[o][(t,w)] += Wc[s] · xa  (M=64 split over waves, N=200, K=64) ----
        #pragma unroll
        for (int nt = 0; nt < NT; ++nt) {
            int tw = nt * 16 + col;                  // B-frag: n = tw
            #pragma unroll
            for (int ks = 0; ks < 2; ++ks) {
                half8 bf = *(const half8*)&xaL[tw * XA_S + ks * 32 + quad * 8]; // k = c
                yacc[nt] = __builtin_amdgcn_mfma_f32_16x16x32_f16(wf[s][ks], bf, yacc[nt], 0, 0, 0);
            }
        }
        __syncthreads();   // xaL is rewritten next s
    }

    // ---- epilogue: BN + residual (from Xl) + ReLU, coalesced stores ----
    const int limit = min(TWN, (Tt - t0) * Vv);
    float* ob = out + (size_t)n * Cc * Tt * Vv + t0 * Vv;
    #pragma unroll
    for (int nt = 0; nt < NT; ++nt) {
        int tw = nt * 16 + col;
        if (tw < limit) {
            int t = tw / Vv;            // compiler -> magic mul
            int w = tw - t * Vv;
            #pragma unroll
            for (int i = 0; i < 4; ++i) {
                int o = wave * 16 + quad * 4 + i;
                float val = yacc[nt][i] * bnsc[o] + bnsh[o];
                val += (float)Xl[o * XL_C + t * XL_T + w];   // residual
                ob[o * Tt * Vv + tw] = fmaxf(val, 0.f);      // contiguous in tw
            }
        }
    }
}

extern "C" void kernel_launch(void* const* d_in, const int* in_sizes, int n_in,
                              void* d_out, int out_size, void* d_ws, size_t ws_size,
                              hipStream_t stream) {
    const float* x     = (const float*)d_in[0];
    const float* A     = (const float*)d_in[1];
    const float* PA1   = (const float*)d_in[2];
    const float* PA2   = (const float*)d_in[3];
    const float* Wc    = (const float*)d_in[4];
    const float* bc    = (const float*)d_in[5];
    const float* gamma = (const float*)d_in[6];
    const float* beta  = (const float*)d_in[7];
    const float* rmean = (const float*)d_in[8];
    const float* rvar  = (const float*)d_in[9];
    float* out = (float*)d_out;

    dim3 grid((Tt + TB - 1) / TB, Nn);   // (38, 64)
    gcn_fused<<<grid, 256, 0, stream>>>(x, A, PA1, PA2, Wc, bc, gamma, beta, rmean, rvar, out);
}